// Round 5
// baseline (208.986 us; speedup 1.0000x reference)
//
#include <hip/hip_runtime.h>

#define B_SZ 2
#define LSEQ 2048
#define NHh 24
#define DHh 64
#define DSs 128
#define TCH 64                  // chunk length
#define NC  (LSEQ / TCH)        // 32 chunks
#define BH  (B_SZ * NHh)        // 48

#define UP  72    // padded row length (shorts) for k1's MFMA operand tiles

// ws layout: S fp32 | G bf16 [bh][c][d][s] | H bf16 (swz) | Bb bf16 (swz) |
//            Cb bf16 (swz) | Xb bf16 [bh][c][d][u] (swz)
#define S_ELEMS    ((size_t)BH * LSEQ)
#define PLANE128   ((size_t)TCH * DSs)      // 8192 els
#define PLANE64    ((size_t)TCH * DHh)      // 4096 els
#define P128_ELEMS ((size_t)BH * NC * PLANE128)
#define P64_ELEMS  ((size_t)BH * NC * PLANE64)
#define WS_S_BYTES (S_ELEMS * 4)
#define WS_REQ     (WS_S_BYTES + 4 * P128_ELEMS * 2 + P64_ELEMS * 2)

typedef __attribute__((ext_vector_type(8))) short bf16x8;
typedef __attribute__((ext_vector_type(4))) float f32x4;

__device__ __forceinline__ unsigned short f2bf(float f) {
    union { float f; unsigned u; } v; v.f = f;
    unsigned r = ((v.u >> 16) & 1u) + 0x7FFFu;
    return (unsigned short)((v.u + r) >> 16);
}
__device__ __forceinline__ float bf2f(unsigned short h) {
    union { unsigned u; float f; } v; v.u = ((unsigned)h) << 16; return v.f;
}
__device__ __forceinline__ unsigned pk2(float a, float b) {
    return (unsigned)f2bf(a) | ((unsigned)f2bf(b) << 16);
}
__device__ __forceinline__ void gload_lds16(const void* g, void* l) {
    __builtin_amdgcn_global_load_lds(
        (const __attribute__((address_space(1))) void*)g,
        (__attribute__((address_space(3))) void*)l, 16, 0, 0);
}

// ====== K1: S scan, G = (f*X)^T.B MFMA, and bf16 preconvert of B/C/X^T ======
__global__ __launch_bounds__(256, 2)
void k1_chunk(const float* __restrict__ x, const float* __restrict__ A,
              const float* __restrict__ Bm, const float* __restrict__ Cm,
              const float* __restrict__ dp, float* __restrict__ S_ws,
              unsigned short* __restrict__ G_ws, unsigned short* __restrict__ Bb_ws,
              unsigned short* __restrict__ Cb_ws, unsigned short* __restrict__ Xb_ws) {
    __shared__ __align__(16) unsigned short sBT[DSs][UP];   // B^T [s][u]
    __shared__ __align__(16) unsigned short sXTf[DHh][UP];  // (f*x)^T [d][u]
    __shared__ __align__(16) unsigned short sXraw[DHh * DHh]; // x^T [d][u] swizzled
    __shared__ float sF[TCH];

    const int c  = blockIdx.x & (NC - 1);
    const int bh = blockIdx.x >> 5;
    const int nh = bh % NHh; const int b = bh / NHh;
    const int tid = threadIdx.x;
    const int lane = tid & 63;
    const int w = tid >> 6;

    const size_t row0 = (size_t)(b * LSEQ + c * TCH) * NHh + nh;

    const int u = tid >> 2;
    const int q = tid & 3;
    const float* Brow = Bm + (row0 + (size_t)u * NHh) * DSs;
    const float* Crow = Cm + (row0 + (size_t)u * NHh) * DSs;
    const float* xrow = x  + (row0 + (size_t)u * NHh) * DHh;
    float4 bv[8], cv[8], xv[4];
    #pragma unroll
    for (int j = 0; j < 8; ++j) bv[j] = *(const float4*)(Brow + (j * 4 + q) * 4);
    #pragma unroll
    for (int j = 0; j < 8; ++j) cv[j] = *(const float4*)(Crow + (j * 4 + q) * 4);
    #pragma unroll
    for (int j = 0; j < 4; ++j) xv[j] = *(const float4*)(xrow + (j * 4 + q) * 4);

    if (tid < 64) {   // wave0: log-decay cumsum
        float a  = A[row0 + (size_t)tid * NHh];
        float z  = a + dp[nh];
        float sp = (z > 20.0f) ? z : log1pf(expf(z));
        float la = -sp * fabsf(a);
        #pragma unroll
        for (int off = 1; off < 64; off <<= 1) {
            float v = __shfl_up(la, off, 64);
            if (lane >= off) la += v;
        }
        S_ws[(size_t)bh * LSEQ + c * TCH + tid] = la;
        float s63 = __shfl(la, 63, 64);
        sF[tid] = expf(s63 - la);
    }
    __syncthreads();

    // bf16 preconvert: global swizzled stores + MFMA LDS tiles
    unsigned short* Bbo = Bb_ws + ((size_t)bh * NC + c) * PLANE128 + (size_t)u * DSs;
    unsigned short* Cbo = Cb_ws + ((size_t)bh * NC + c) * PLANE128 + (size_t)u * DSs;
    #pragma unroll
    for (int j = 0; j < 8; ++j) {
        const int sl   = j * 4 + q;            // 8-byte-half index 0..31
        const int s    = sl * 4;
        const int phys = ((sl >> 1) ^ (u & 7)) * 8 + (sl & 1) * 4;  // shorts
        uint2 bp; bp.x = pk2(bv[j].x, bv[j].y); bp.y = pk2(bv[j].z, bv[j].w);
        uint2 cp; cp.x = pk2(cv[j].x, cv[j].y); cp.y = pk2(cv[j].z, cv[j].w);
        *(uint2*)(Bbo + phys) = bp;
        *(uint2*)(Cbo + phys) = cp;
        sBT[s + 0][u] = f2bf(bv[j].x);
        sBT[s + 1][u] = f2bf(bv[j].y);
        sBT[s + 2][u] = f2bf(bv[j].z);
        sBT[s + 3][u] = f2bf(bv[j].w);
    }
    const float f = sF[u];
    #pragma unroll
    for (int j = 0; j < 4; ++j) {
        const int d0 = (j * 4 + q) * 4;
        const float xs[4] = {xv[j].x, xv[j].y, xv[j].z, xv[j].w};
        #pragma unroll
        for (int r = 0; r < 4; ++r) {
            const int d = d0 + r;
            sXTf[d][u] = f2bf(xs[r] * f);
            sXraw[d * DHh + (((u >> 3) ^ (d & 7)) * 8) + (u & 7)] = f2bf(xs[r]);
        }
    }
    __syncthreads();

    // MFMA: G[d][s] = sum_u Xf^T[d][u] * B^T[s][u]; wave w owns d rows [16w,16w+16)
    const int fr = lane >> 4, fc = lane & 15;
    bf16x8 afr0 = *(const bf16x8*)&sXTf[16 * w + fc][fr * 8];
    bf16x8 afr1 = *(const bf16x8*)&sXTf[16 * w + fc][32 + fr * 8];
    #pragma unroll
    for (int st = 0; st < 8; ++st) {
        f32x4 acc = {0.f, 0.f, 0.f, 0.f};
        bf16x8 b0 = *(const bf16x8*)&sBT[st * 16 + fc][fr * 8];
        bf16x8 b1 = *(const bf16x8*)&sBT[st * 16 + fc][32 + fr * 8];
        acc = __builtin_amdgcn_mfma_f32_16x16x32_bf16(afr0, b0, acc, 0, 0, 0);
        acc = __builtin_amdgcn_mfma_f32_16x16x32_bf16(afr1, b1, acc, 0, 0, 0);
        unsigned short* gout = G_ws +
            (((size_t)bh * NC + c) * DHh + 16 * w + fr * 4) * DSs + st * 16 + fc;
        #pragma unroll
        for (int r = 0; r < 4; ++r) gout[(size_t)r * DSs] = f2bf(acc[r]);
    }

    // X^T bf16 copy-out (coalesced)
    uint4* Xbo = (uint4*)(Xb_ws + ((size_t)bh * NC + c) * PLANE64);
    const uint4* srcX = (const uint4*)sXraw;
    #pragma unroll
    for (int i = 0; i < 2; ++i) Xbo[i * 256 + tid] = srcX[i * 256 + tid];
}

// ====== K2: chunk-level scan; E precomputed, depth-2 prefetch; H swizzled ======
__global__ __launch_bounds__(256)
void k2_scan(const float* __restrict__ S_ws, const unsigned short* __restrict__ G_ws,
             unsigned short* __restrict__ H_ws) {
    __shared__ float sE[NC];
    const int dblk = blockIdx.x & 3;
    const int bh   = blockIdx.x >> 2;
    const int tid  = threadIdx.x;
    const int d    = dblk * 16 + (tid >> 4);
    const int s0   = (tid & 15) * 8;

    if (tid < NC) sE[tid] = expf(S_ws[(size_t)bh * LSEQ + tid * TCH + (TCH - 1)]);
    __syncthreads();

    const size_t cstride = PLANE128;
    const size_t gbase = (size_t)bh * NC * PLANE128 + (size_t)d * DSs + s0;
    const int    physs = ((s0 >> 3) ^ (d & 7)) * 8;
    const size_t hbase = (size_t)bh * NC * PLANE128 + (size_t)d * DSs + physs;

    float h[8];
    #pragma unroll
    for (int k = 0; k < 8; ++k) h[k] = 0.f;

    uint4 g0 = *(const uint4*)(G_ws + gbase);
    uint4 g1 = *(const uint4*)(G_ws + gbase + cstride);
    for (int c = 0; c < NC; ++c) {
        uint4 gn = (c + 2 < NC) ? *(const uint4*)(G_ws + gbase + (size_t)(c + 2) * cstride) : g0;
        const float e = sE[c];
        uint4 p;
        p.x = pk2(h[0], h[1]); p.y = pk2(h[2], h[3]);
        p.z = pk2(h[4], h[5]); p.w = pk2(h[6], h[7]);
        *(uint4*)(H_ws + hbase + (size_t)c * cstride) = p;
        const unsigned gu[4] = {g0.x, g0.y, g0.z, g0.w};
        #pragma unroll
        for (int k = 0; k < 4; ++k) {
            h[2 * k]     = fmaf(e, h[2 * k],     bf2f((unsigned short)(gu[k] & 0xffff)));
            h[2 * k + 1] = fmaf(e, h[2 * k + 1], bf2f((unsigned short)(gu[k] >> 16)));
        }
        g0 = g1; g1 = gn;
    }
}

// ====== K3: all-bf16 async staging; W = mask.exp o (C.B^T); y = W.X + E o (C.H^T) ======
__global__ __launch_bounds__(256, 2)
void k3_y(const unsigned short* __restrict__ Bb_ws, const unsigned short* __restrict__ Cb_ws,
          const unsigned short* __restrict__ Xb_ws, const unsigned short* __restrict__ H_ws,
          const float* __restrict__ S_ws, float* __restrict__ y) {
    __shared__ __align__(16) unsigned short sC[TCH][DSs];   // swizzled
    __shared__ __align__(16) unsigned short sB[TCH][DSs];   // swizzled
    __shared__ __align__(16) unsigned short sH[DHh][DSs];   // swizzled
    __shared__ __align__(16) unsigned short sXT[DHh][DHh];  // swizzled
    __shared__ __align__(16) unsigned short sW[TCH][UP];    // padded, per-wave rows
    __shared__ float sS[TCH];
    __shared__ float sEt[TCH];

    const int c  = blockIdx.x & (NC - 1);
    const int bh = blockIdx.x >> 5;
    const int nh = bh % NHh; const int b = bh / NHh;
    const int tid = threadIdx.x;
    const int lane = tid & 63;
    const int w = tid >> 6;

    const size_t p128 = ((size_t)bh * NC + c) * PLANE128;
    const size_t p64  = ((size_t)bh * NC + c) * PLANE64;

    // async stage: 14 x 1KB calls per wave
    #pragma unroll
    for (int j = 0; j < 4; ++j) {
        const int off = (w * 4 + j) * 512;            // elements
        gload_lds16(Cb_ws + p128 + off + lane * 8, ((char*)&sC[0][0]) + off * 2);
        gload_lds16(Bb_ws + p128 + off + lane * 8, ((char*)&sB[0][0]) + off * 2);
        gload_lds16(H_ws  + p128 + off + lane * 8, ((char*)&sH[0][0]) + off * 2);
    }
    #pragma unroll
    for (int j = 0; j < 2; ++j) {
        const int off = (w * 2 + j) * 512;
        gload_lds16(Xb_ws + p64 + off + lane * 8, ((char*)&sXT[0][0]) + off * 2);
    }
    if (tid < 64) {
        float sv = S_ws[(size_t)bh * LSEQ + c * TCH + tid];
        sS[tid]  = sv;
        sEt[tid] = expf(sv);
    }
    __syncthreads();

    const int fr = lane >> 4, fc = lane & 15;
    const int t0w = 16 * w;
    const int swz = fc & 7;     // all tile rows used are (16*k + fc) -> row&7 == fc&7

    // ---- W phase ----
    bf16x8 ca[4];
    #pragma unroll
    for (int kb = 0; kb < 4; ++kb)
        ca[kb] = *(const bf16x8*)&sC[t0w + fc][((kb * 4 + fr) ^ swz) * 8];
    float st4[4];
    #pragma unroll
    for (int r = 0; r < 4; ++r) st4[r] = sS[t0w + fr * 4 + r];

    #pragma unroll
    for (int ut = 0; ut < 4; ++ut) {
        const int u0 = ut * 16;
        unsigned short wv[4] = {0, 0, 0, 0};
        if (ut <= w) {
            f32x4 acc = {0.f, 0.f, 0.f, 0.f};
            #pragma unroll
            for (int kb = 0; kb < 4; ++kb) {
                bf16x8 bb = *(const bf16x8*)&sB[u0 + fc][((kb * 4 + fr) ^ swz) * 8];
                acc = __builtin_amdgcn_mfma_f32_16x16x32_bf16(ca[kb], bb, acc, 0, 0, 0);
            }
            const float su = sS[u0 + fc];
            const int   uu = u0 + fc;
            #pragma unroll
            for (int r = 0; r < 4; ++r) {
                const int t = t0w + fr * 4 + r;
                const float dd = fminf(st4[r] - su, 0.f);
                wv[r] = f2bf((uu <= t) ? acc[r] * expf(dd) : 0.f);
            }
        }
        #pragma unroll
        for (int r = 0; r < 4; ++r) sW[t0w + fr * 4 + r][u0 + fc] = wv[r];
    }
    // no barrier: each wave reads only the sW rows it wrote

    // ---- Y phase ----
    bf16x8 wa0 = *(const bf16x8*)&sW[t0w + fc][fr * 8];
    bf16x8 wa1;
    if (w >= 2) wa1 = *(const bf16x8*)&sW[t0w + fc][32 + fr * 8];
    float et4[4];
    #pragma unroll
    for (int r = 0; r < 4; ++r) et4[r] = sEt[t0w + fr * 4 + r];

    const size_t row0 = (size_t)(b * LSEQ + c * TCH) * NHh + nh;
    #pragma unroll
    for (int dt = 0; dt < 4; ++dt) {
        const int d0 = dt * 16;
        f32x4 acc = {0.f, 0.f, 0.f, 0.f};
        #pragma unroll
        for (int kb = 0; kb < 4; ++kb) {
            bf16x8 hb = *(const bf16x8*)&sH[d0 + fc][((kb * 4 + fr) ^ swz) * 8];
            acc = __builtin_amdgcn_mfma_f32_16x16x32_bf16(ca[kb], hb, acc, 0, 0, 0);
        }
        #pragma unroll
        for (int r = 0; r < 4; ++r) acc[r] *= et4[r];
        bf16x8 xb0 = *(const bf16x8*)&sXT[d0 + fc][((0 + fr) ^ swz) * 8];
        acc = __builtin_amdgcn_mfma_f32_16x16x32_bf16(wa0, xb0, acc, 0, 0, 0);
        if (w >= 2) {
            bf16x8 xb1 = *(const bf16x8*)&sXT[d0 + fc][((4 + fr) ^ swz) * 8];
            acc = __builtin_amdgcn_mfma_f32_16x16x32_bf16(wa1, xb1, acc, 0, 0, 0);
        }
        float* yout = y + (row0 + (size_t)(t0w + fr * 4) * NHh) * DHh + d0 + fc;
        #pragma unroll
        for (int r = 0; r < 4; ++r) yout[(size_t)r * NHh * DHh] = acc[r];
    }
}

// ====== fallback (R2 kernel, used only if ws too small) ======
__device__ __forceinline__ void gload_lds4(const float* g, float* l) {
    __builtin_amdgcn_global_load_lds(
        (const __attribute__((address_space(1))) void*)g,
        (__attribute__((address_space(3))) void*)l, 4, 0, 0);
}
#define F_DBLK 4
#define F_DPW 16
#define F_TCH 32
#define F_NCH (LSEQ / F_TCH)
__global__ __launch_bounds__(256, 1)
void ssm_scan_fb(const float* __restrict__ x, const float* __restrict__ A,
                 const float* __restrict__ Bm, const float* __restrict__ Cm,
                 const float* __restrict__ dp, float* __restrict__ y) {
    __shared__ float s_abar[LSEQ];
    __shared__ float s_B[2][F_TCH][DSs];
    __shared__ float s_C[2][F_TCH][DSs];
    __shared__ float s_x[2][F_TCH][F_DPW];
    const int blk = blockIdx.x;
    const int dblk = blk % F_DBLK, bh = blk / F_DBLK;
    const int nh = bh % NHh, b = bh / NHh;
    const float dpv = dp[nh];
    for (int i = threadIdx.x; i < LSEQ; i += 256) {
        float a = A[(b * LSEQ + i) * NHh + nh];
        float z = a + dpv;
        float sp = (z > 20.0f) ? z : log1pf(expf(z));
        s_abar[i] = expf(-sp * fabsf(a));
    }
    const int tid = threadIdx.x, wid = tid >> 6, lane = tid & 63;
    const int dloc = tid >> 4, sg = tid & 15, sb = sg * 8;
    const size_t bh_off = (size_t)(b * LSEQ) * NHh + nh;
    const float* Bbase = Bm + bh_off * DSs;
    const float* Cbase = Cm + bh_off * DSs;
    const float* xbase = x + bh_off * DHh + dblk * F_DPW;
    float* yp = y + bh_off * DHh + dblk * F_DPW + dloc;
    const int RSTRIDE = NHh * DSs, XSTRIDE = NHh * DHh;
    auto stage = [&](int buf, int t0) {
        #pragma unroll
        for (int j = 0; j < 4; ++j) {
            const int r0 = (wid * 4 + j) * 2, r = r0 + (lane >> 5), col = (lane & 31) * 4;
            gload_lds16(Bbase + (size_t)(t0 + r) * RSTRIDE + col, &s_B[buf][r0][0]);
            gload_lds16(Cbase + (size_t)(t0 + r) * RSTRIDE + col, &s_C[buf][r0][0]);
        }
        #pragma unroll
        for (int j = 0; j < 2; ++j) {
            const int idx = (wid * 2 + j) * 64 + lane, t = idx >> 4, dc = idx & 15;
            gload_lds4(xbase + (size_t)(t0 + t) * XSTRIDE + dc, &s_x[buf][(wid * 2 + j) * 4][0]);
        }
    };
    stage(0, 0);
    __syncthreads();
    float h0=0,h1=0,h2=0,h3=0,h4=0,h5=0,h6=0,h7=0;
    for (int c = 0; c < F_NCH; ++c) {
        const int buf = c & 1;
        if (c + 1 < F_NCH) stage(buf ^ 1, (c + 1) * F_TCH);
        const int t0 = c * F_TCH;
        #pragma unroll 4
        for (int tt = 0; tt < F_TCH; ++tt) {
            const int t = t0 + tt;
            const float a = s_abar[t], xd = s_x[buf][tt][dloc];
            const float4* Br = (const float4*)&s_B[buf][tt][sb];
            const float4* Cr = (const float4*)&s_C[buf][tt][sb];
            const float4 B0 = Br[0], B1 = Br[1], C0 = Cr[0], C1 = Cr[1];
            h0 = fmaf(a, h0, xd * B0.x); h1 = fmaf(a, h1, xd * B0.y);
            h2 = fmaf(a, h2, xd * B0.z); h3 = fmaf(a, h3, xd * B0.w);
            h4 = fmaf(a, h4, xd * B1.x); h5 = fmaf(a, h5, xd * B1.y);
            h6 = fmaf(a, h6, xd * B1.z); h7 = fmaf(a, h7, xd * B1.w);
            float p0 = h0 * C0.x; p0 = fmaf(h1, C0.y, p0); p0 = fmaf(h2, C0.z, p0); p0 = fmaf(h3, C0.w, p0);
            float p1 = h4 * C1.x; p1 = fmaf(h5, C1.y, p1); p1 = fmaf(h6, C1.z, p1); p1 = fmaf(h7, C1.w, p1);
            float p = p0 + p1;
            p += __shfl_xor(p, 1, 64); p += __shfl_xor(p, 2, 64);
            p += __shfl_xor(p, 4, 64); p += __shfl_xor(p, 8, 64);
            if (sg == 0) yp[(size_t)t * XSTRIDE] = p;
        }
        __syncthreads();
    }
}

extern "C" void kernel_launch(void* const* d_in, const int* in_sizes, int n_in,
                              void* d_out, int out_size, void* d_ws, size_t ws_size,
                              hipStream_t stream) {
    const float* x  = (const float*)d_in[0];
    const float* A  = (const float*)d_in[1];
    const float* Bm = (const float*)d_in[2];
    const float* Cm = (const float*)d_in[3];
    const float* dp = (const float*)d_in[4];
    float* y = (float*)d_out;

    if (ws_size >= WS_REQ) {
        float* S_ws = (float*)d_ws;
        unsigned short* G_ws  = (unsigned short*)((char*)d_ws + WS_S_BYTES);
        unsigned short* H_ws  = G_ws + P128_ELEMS;
        unsigned short* Bb_ws = H_ws + P128_ELEMS;
        unsigned short* Cb_ws = Bb_ws + P128_ELEMS;
        unsigned short* Xb_ws = Cb_ws + P128_ELEMS;
        hipLaunchKernelGGL(k1_chunk, dim3(BH * NC), dim3(256), 0, stream,
                           x, A, Bm, Cm, dp, S_ws, G_ws, Bb_ws, Cb_ws, Xb_ws);
        hipLaunchKernelGGL(k2_scan, dim3(BH * 4), dim3(256), 0, stream,
                           S_ws, G_ws, H_ws);
        hipLaunchKernelGGL(k3_y, dim3(BH * NC), dim3(256), 0, stream,
                           Bb_ws, Cb_ws, Xb_ws, H_ws, S_ws, y);
    } else {
        hipLaunchKernelGGL(ssm_scan_fb, dim3(BH * F_DBLK), dim3(256), 0, stream,
                           x, A, Bm, Cm, dp, y);
    }
}

// Round 6
// 190.047 us; speedup vs baseline: 1.0997x; 1.0997x over previous
//
#include <hip/hip_runtime.h>

#define B_SZ 2
#define LSEQ 2048
#define NHh 24
#define DHh 64
#define DSs 128
#define TCH 64                  // chunk length
#define NC  (LSEQ / TCH)        // 32 chunks
#define BH  (B_SZ * NHh)        // 48

#define SP  136   // padded row (shorts) for k=128 tiles in k3
#define UP  72    // padded row (shorts) for k=64 tiles
#define GP  144   // padded row (shorts) for k1's G relayout tile (288 B stride)

// ws layout: S fp32 | G bf16 [bh][c][d][s] | H bf16 (same layout)
#define S_ELEMS    ((size_t)BH * LSEQ)
#define PLANE128   ((size_t)TCH * DSs)      // 8192 els
#define P128_ELEMS ((size_t)BH * NC * PLANE128)
#define WS_S_BYTES (S_ELEMS * 4)
#define WS_REQ     (WS_S_BYTES + 2 * P128_ELEMS * 2)

typedef __attribute__((ext_vector_type(8))) short bf16x8;
typedef __attribute__((ext_vector_type(4))) float f32x4;

__device__ __forceinline__ unsigned short f2bf(float f) {
    union { float f; unsigned u; } v; v.f = f;
    unsigned r = ((v.u >> 16) & 1u) + 0x7FFFu;
    return (unsigned short)((v.u + r) >> 16);
}
__device__ __forceinline__ float bf2f(unsigned short h) {
    union { unsigned u; float f; } v; v.u = ((unsigned)h) << 16; return v.f;
}
__device__ __forceinline__ unsigned pk2(float a, float b) {
    return (unsigned)f2bf(a) | ((unsigned)f2bf(b) << 16);
}
__device__ __forceinline__ void gload_lds16(const void* g, void* l) {
    __builtin_amdgcn_global_load_lds(
        (const __attribute__((address_space(1))) void*)g,
        (__attribute__((address_space(3))) void*)l, 16, 0, 0);
}

// ====== K1: S scan + G = (f*X)^T.B via MFMA; G stored coalesced via LDS relayout ======
__global__ __launch_bounds__(256, 2)
void k1_chunk(const float* __restrict__ x, const float* __restrict__ A,
              const float* __restrict__ Bm, const float* __restrict__ dp,
              float* __restrict__ S_ws, unsigned short* __restrict__ G_ws) {
    __shared__ __align__(16) unsigned short sBT[DSs][UP];   // B^T [s][u]
    __shared__ __align__(16) unsigned short sXTf[DHh][UP];  // (f*x)^T [d][u]
    __shared__ __align__(16) unsigned short sG[DHh][GP];    // G [d][s] relayout tile
    __shared__ float sF[TCH];

    const int c  = blockIdx.x & (NC - 1);
    const int bh = blockIdx.x >> 5;
    const int nh = bh % NHh; const int b = bh / NHh;
    const int tid = threadIdx.x;
    const int lane = tid & 63;
    const int w = tid >> 6;

    const size_t row0 = (size_t)(b * LSEQ + c * TCH) * NHh + nh;

    // register-staged global loads (row u per 4 lanes)
    const int u = tid >> 2;
    const int q = tid & 3;
    const float* Brow = Bm + (row0 + (size_t)u * NHh) * DSs;
    const float* xrow = x  + (row0 + (size_t)u * NHh) * DHh;
    float4 bv[8], xv[4];
    #pragma unroll
    for (int j = 0; j < 8; ++j) bv[j] = *(const float4*)(Brow + (j * 4 + q) * 4);
    #pragma unroll
    for (int j = 0; j < 4; ++j) xv[j] = *(const float4*)(xrow + (j * 4 + q) * 4);

    if (tid < 64) {   // wave0: log-decay cumsum
        float a  = A[row0 + (size_t)tid * NHh];
        float z  = a + dp[nh];
        float sp = (z > 20.0f) ? z : log1pf(expf(z));
        float la = -sp * fabsf(a);
        #pragma unroll
        for (int off = 1; off < 64; off <<= 1) {
            float v = __shfl_up(la, off, 64);
            if (lane >= off) la += v;
        }
        S_ws[(size_t)bh * LSEQ + c * TCH + tid] = la;
        float s63 = __shfl(la, 63, 64);
        sF[tid] = expf(s63 - la);
    }
    __syncthreads();

    // transpose-convert into LDS
    #pragma unroll
    for (int j = 0; j < 8; ++j) {
        const int s = (j * 4 + q) * 4;
        sBT[s + 0][u] = f2bf(bv[j].x);
        sBT[s + 1][u] = f2bf(bv[j].y);
        sBT[s + 2][u] = f2bf(bv[j].z);
        sBT[s + 3][u] = f2bf(bv[j].w);
    }
    const float f = sF[u];
    #pragma unroll
    for (int j = 0; j < 4; ++j) {
        const int d = (j * 4 + q) * 4;
        sXTf[d + 0][u] = f2bf(xv[j].x * f);
        sXTf[d + 1][u] = f2bf(xv[j].y * f);
        sXTf[d + 2][u] = f2bf(xv[j].z * f);
        sXTf[d + 3][u] = f2bf(xv[j].w * f);
    }
    __syncthreads();

    // MFMA: G[d][s] = sum_u Xf^T[d][u] * B^T[s][u]; wave w owns d rows [16w,16w+16)
    const int fr = lane >> 4, fc = lane & 15;
    bf16x8 afr0 = *(const bf16x8*)&sXTf[16 * w + fc][fr * 8];
    bf16x8 afr1 = *(const bf16x8*)&sXTf[16 * w + fc][32 + fr * 8];
    #pragma unroll
    for (int st = 0; st < 8; ++st) {
        f32x4 acc = {0.f, 0.f, 0.f, 0.f};
        bf16x8 b0 = *(const bf16x8*)&sBT[st * 16 + fc][fr * 8];
        bf16x8 b1 = *(const bf16x8*)&sBT[st * 16 + fc][32 + fr * 8];
        acc = __builtin_amdgcn_mfma_f32_16x16x32_bf16(afr0, b0, acc, 0, 0, 0);
        acc = __builtin_amdgcn_mfma_f32_16x16x32_bf16(afr1, b1, acc, 0, 0, 0);
        #pragma unroll
        for (int r = 0; r < 4; ++r)
            sG[16 * w + fr * 4 + r][st * 16 + fc] = f2bf(acc[r]);
    }
    __syncthreads();

    // coalesced copy-out: 64 rows x 128 shorts -> uint4
    const size_t gplane = ((size_t)bh * NC + c) * PLANE128;
    #pragma unroll
    for (int i = 0; i < 4; ++i) {
        const int idx = i * 256 + tid;
        const int row = idx >> 4;
        const int col = (idx & 15) * 8;
        *(uint4*)(G_ws + gplane + (size_t)row * DSs + col) = *(const uint4*)&sG[row][col];
    }
}

// ====== K2: chunk-level scan (768 blocks x 64 thr); E hoisted; depth-2 prefetch ======
__global__ __launch_bounds__(64)
void k2_scan(const float* __restrict__ S_ws, const unsigned short* __restrict__ G_ws,
             unsigned short* __restrict__ H_ws) {
    __shared__ float sE[NC];
    const int dblk = blockIdx.x & 15;
    const int bh   = blockIdx.x >> 4;
    const int tid  = threadIdx.x;
    const int d    = dblk * 4 + (tid >> 4);
    const int s0   = (tid & 15) * 8;

    if (tid < NC) sE[tid] = expf(S_ws[(size_t)bh * LSEQ + tid * TCH + (TCH - 1)]);
    __syncthreads();

    const size_t cstride = PLANE128;
    const size_t base = (size_t)bh * NC * PLANE128 + (size_t)d * DSs + s0;

    float h[8];
    #pragma unroll
    for (int k = 0; k < 8; ++k) h[k] = 0.f;

    uint4 g0 = *(const uint4*)(G_ws + base);
    uint4 g1 = *(const uint4*)(G_ws + base + cstride);
    for (int c = 0; c < NC; ++c) {
        uint4 gn = (c + 2 < NC) ? *(const uint4*)(G_ws + base + (size_t)(c + 2) * cstride) : g0;
        const float e = sE[c];
        uint4 p;
        p.x = pk2(h[0], h[1]); p.y = pk2(h[2], h[3]);
        p.z = pk2(h[4], h[5]); p.w = pk2(h[6], h[7]);
        *(uint4*)(H_ws + base + (size_t)c * cstride) = p;
        const unsigned gu[4] = {g0.x, g0.y, g0.z, g0.w};
        #pragma unroll
        for (int k = 0; k < 4; ++k) {
            h[2 * k]     = fmaf(e, h[2 * k],     bf2f((unsigned short)(gu[k] & 0xffff)));
            h[2 * k + 1] = fmaf(e, h[2 * k + 1], bf2f((unsigned short)(gu[k] >> 16)));
        }
        g0 = g1; g1 = gn;
    }
}

// ====== K3: W = mask.exp o (C.B^T); y = W.X + E o (C.H^T), all MFMA (R4 version) ======
__global__ __launch_bounds__(256, 2)
void k3_y(const float* __restrict__ x, const float* __restrict__ Bm,
          const float* __restrict__ Cm, const float* __restrict__ S_ws,
          const unsigned short* __restrict__ H_ws, float* __restrict__ y) {
    __shared__ __align__(16) unsigned short sC[TCH][SP];   // C [t][s] bf16
    __shared__ __align__(16) unsigned short sB[TCH][SP];   // B [u][s] bf16
    __shared__ __align__(16) unsigned short sH[DHh][SP];   // H [d][s] bf16
    __shared__ __align__(16) unsigned short sW[TCH][UP];   // W [t][u] bf16
    __shared__ __align__(16) unsigned short sXT[DHh][UP];  // X^T [d][u] bf16
    __shared__ float sS[TCH];
    __shared__ float sEt[TCH];

    const int c  = blockIdx.x & (NC - 1);
    const int bh = blockIdx.x >> 5;
    const int nh = bh % NHh; const int b = bh / NHh;
    const int tid = threadIdx.x;
    const int lane = tid & 63;
    const int w = tid >> 6;

    const size_t row0 = (size_t)(b * LSEQ + c * TCH) * NHh + nh;

    // global loads to registers
    const int rr = tid >> 2;    // row (t for C/B/X; d for H)
    const int q  = tid & 3;
    const float* Crow = Cm + (row0 + (size_t)rr * NHh) * DSs;
    const float* Brow = Bm + (row0 + (size_t)rr * NHh) * DSs;
    const float* xrow = x  + (row0 + (size_t)rr * NHh) * DHh;
    const unsigned short* Hrow = H_ws + (((size_t)bh * NC + c) * DHh + rr) * DSs;
    float4 cv[8], bv[8], xv[4];
    uint4  hv[4];
    #pragma unroll
    for (int j = 0; j < 8; ++j) cv[j] = *(const float4*)(Crow + (j * 4 + q) * 4);
    #pragma unroll
    for (int j = 0; j < 8; ++j) bv[j] = *(const float4*)(Brow + (j * 4 + q) * 4);
    #pragma unroll
    for (int j = 0; j < 4; ++j) xv[j] = *(const float4*)(xrow + (j * 4 + q) * 4);
    #pragma unroll
    for (int j = 0; j < 4; ++j) hv[j] = *(const uint4*)(Hrow + (j * 4 + q) * 8);

    if (tid < 64) {
        float sv = S_ws[(size_t)bh * LSEQ + c * TCH + tid];
        sS[tid]  = sv;
        sEt[tid] = expf(sv);
    }

    // convert/write LDS
    #pragma unroll
    for (int j = 0; j < 8; ++j) {
        const int s = (j * 4 + q) * 4;
        *(uint2*)&sC[rr][s] = make_uint2(pk2(cv[j].x, cv[j].y), pk2(cv[j].z, cv[j].w));
        *(uint2*)&sB[rr][s] = make_uint2(pk2(bv[j].x, bv[j].y), pk2(bv[j].z, bv[j].w));
    }
    #pragma unroll
    for (int j = 0; j < 4; ++j)
        *(uint4*)&sH[rr][(j * 4 + q) * 8] = hv[j];
    #pragma unroll
    for (int j = 0; j < 4; ++j) {
        const int d = (j * 4 + q) * 4;
        sXT[d + 0][rr] = f2bf(xv[j].x);
        sXT[d + 1][rr] = f2bf(xv[j].y);
        sXT[d + 2][rr] = f2bf(xv[j].z);
        sXT[d + 3][rr] = f2bf(xv[j].w);
    }
    __syncthreads();

    const int fr = lane >> 4, fc = lane & 15;
    const int t0w = 16 * w;

    // ---- W phase: wave w owns t-rows [t0w, t0w+16) ----
    bf16x8 ca[4];
    #pragma unroll
    for (int kb = 0; kb < 4; ++kb)
        ca[kb] = *(const bf16x8*)&sC[t0w + fc][kb * 32 + fr * 8];
    float st4[4];
    #pragma unroll
    for (int r = 0; r < 4; ++r) st4[r] = sS[t0w + fr * 4 + r];

    #pragma unroll
    for (int ut = 0; ut < 4; ++ut) {
        const int u0 = ut * 16;
        unsigned short wv[4] = {0, 0, 0, 0};
        if (ut <= w) {
            f32x4 acc = {0.f, 0.f, 0.f, 0.f};
            #pragma unroll
            for (int kb = 0; kb < 4; ++kb) {
                bf16x8 bb = *(const bf16x8*)&sB[u0 + fc][kb * 32 + fr * 8];
                acc = __builtin_amdgcn_mfma_f32_16x16x32_bf16(ca[kb], bb, acc, 0, 0, 0);
            }
            const float su = sS[u0 + fc];
            const int   uu = u0 + fc;
            #pragma unroll
            for (int r = 0; r < 4; ++r) {
                const int t = t0w + fr * 4 + r;
                const float dd = fminf(st4[r] - su, 0.f);
                wv[r] = f2bf((uu <= t) ? acc[r] * expf(dd) : 0.f);
            }
        }
        #pragma unroll
        for (int r = 0; r < 4; ++r) sW[t0w + fr * 4 + r][u0 + fc] = wv[r];
    }
    // no barrier: each wave reads only the sW rows it wrote

    // ---- Y phase: acc = C.H^T (K=128), scale by E_t, then += W.X (K=64) ----
    bf16x8 wa0 = *(const bf16x8*)&sW[t0w + fc][fr * 8];
    bf16x8 wa1;
    if (w >= 2) wa1 = *(const bf16x8*)&sW[t0w + fc][32 + fr * 8];
    float et4[4];
    #pragma unroll
    for (int r = 0; r < 4; ++r) et4[r] = sEt[t0w + fr * 4 + r];

    #pragma unroll
    for (int dt = 0; dt < 4; ++dt) {
        const int d0 = dt * 16;
        f32x4 acc = {0.f, 0.f, 0.f, 0.f};
        #pragma unroll
        for (int kb = 0; kb < 4; ++kb) {
            bf16x8 hb = *(const bf16x8*)&sH[d0 + fc][kb * 32 + fr * 8];
            acc = __builtin_amdgcn_mfma_f32_16x16x32_bf16(ca[kb], hb, acc, 0, 0, 0);
        }
        #pragma unroll
        for (int r = 0; r < 4; ++r) acc[r] *= et4[r];
        bf16x8 xb0 = *(const bf16x8*)&sXT[d0 + fc][fr * 8];
        acc = __builtin_amdgcn_mfma_f32_16x16x32_bf16(wa0, xb0, acc, 0, 0, 0);
        if (w >= 2) {
            bf16x8 xb1 = *(const bf16x8*)&sXT[d0 + fc][32 + fr * 8];
            acc = __builtin_amdgcn_mfma_f32_16x16x32_bf16(wa1, xb1, acc, 0, 0, 0);
        }
        float* yout = y + (row0 + (size_t)(t0w + fr * 4) * NHh) * DHh + d0 + fc;
        #pragma unroll
        for (int r = 0; r < 4; ++r) yout[(size_t)r * NHh * DHh] = acc[r];
    }
}

// ====== fallback (R2 kernel, used only if ws too small) ======
__device__ __forceinline__ void gload_lds4(const float* g, float* l) {
    __builtin_amdgcn_global_load_lds(
        (const __attribute__((address_space(1))) void*)g,
        (__attribute__((address_space(3))) void*)l, 4, 0, 0);
}
#define F_DBLK 4
#define F_DPW 16
#define F_TCH 32
#define F_NCH (LSEQ / F_TCH)
__global__ __launch_bounds__(256, 1)
void ssm_scan_fb(const float* __restrict__ x, const float* __restrict__ A,
                 const float* __restrict__ Bm, const float* __restrict__ Cm,
                 const float* __restrict__ dp, float* __restrict__ y) {
    __shared__ float s_abar[LSEQ];
    __shared__ float s_B[2][F_TCH][DSs];
    __shared__ float s_C[2][F_TCH][DSs];
    __shared__ float s_x[2][F_TCH][F_DPW];
    const int blk = blockIdx.x;
    const int dblk = blk % F_DBLK, bh = blk / F_DBLK;
    const int nh = bh % NHh, b = bh / NHh;
    const float dpv = dp[nh];
    for (int i = threadIdx.x; i < LSEQ; i += 256) {
        float a = A[(b * LSEQ + i) * NHh + nh];
        float z = a + dpv;
        float sp = (z > 20.0f) ? z : log1pf(expf(z));
        s_abar[i] = expf(-sp * fabsf(a));
    }
    const int tid = threadIdx.x, wid = tid >> 6, lane = tid & 63;
    const int dloc = tid >> 4, sg = tid & 15, sb = sg * 8;
    const size_t bh_off = (size_t)(b * LSEQ) * NHh + nh;
    const float* Bbase = Bm + bh_off * DSs;
    const float* Cbase = Cm + bh_off * DSs;
    const float* xbase = x + bh_off * DHh + dblk * F_DPW;
    float* yp = y + bh_off * DHh + dblk * F_DPW + dloc;
    const int RSTRIDE = NHh * DSs, XSTRIDE = NHh * DHh;
    auto stage = [&](int buf, int t0) {
        #pragma unroll
        for (int j = 0; j < 4; ++j) {
            const int r0 = (wid * 4 + j) * 2, r = r0 + (lane >> 5), col = (lane & 31) * 4;
            gload_lds16(Bbase + (size_t)(t0 + r) * RSTRIDE + col, &s_B[buf][r0][0]);
            gload_lds16(Cbase + (size_t)(t0 + r) * RSTRIDE + col, &s_C[buf][r0][0]);
        }
        #pragma unroll
        for (int j = 0; j < 2; ++j) {
            const int idx = (wid * 2 + j) * 64 + lane, t = idx >> 4, dc = idx & 15;
            gload_lds4(xbase + (size_t)(t0 + t) * XSTRIDE + dc, &s_x[buf][(wid * 2 + j) * 4][0]);
        }
    };
    stage(0, 0);
    __syncthreads();
    float h0=0,h1=0,h2=0,h3=0,h4=0,h5=0,h6=0,h7=0;
    for (int c = 0; c < F_NCH; ++c) {
        const int buf = c & 1;
        if (c + 1 < F_NCH) stage(buf ^ 1, (c + 1) * F_TCH);
        const int t0 = c * F_TCH;
        #pragma unroll 4
        for (int tt = 0; tt < F_TCH; ++tt) {
            const int t = t0 + tt;
            const float a = s_abar[t], xd = s_x[buf][tt][dloc];
            const float4* Br = (const float4*)&s_B[buf][tt][sb];
            const float4* Cr = (const float4*)&s_C[buf][tt][sb];
            const float4 B0 = Br[0], B1 = Br[1], C0 = Cr[0], C1 = Cr[1];
            h0 = fmaf(a, h0, xd * B0.x); h1 = fmaf(a, h1, xd * B0.y);
            h2 = fmaf(a, h2, xd * B0.z); h3 = fmaf(a, h3, xd * B0.w);
            h4 = fmaf(a, h4, xd * B1.x); h5 = fmaf(a, h5, xd * B1.y);
            h6 = fmaf(a, h6, xd * B1.z); h7 = fmaf(a, h7, xd * B1.w);
            float p0 = h0 * C0.x; p0 = fmaf(h1, C0.y, p0); p0 = fmaf(h2, C0.z, p0); p0 = fmaf(h3, C0.w, p0);
            float p1 = h4 * C1.x; p1 = fmaf(h5, C1.y, p1); p1 = fmaf(h6, C1.z, p1); p1 = fmaf(h7, C1.w, p1);
            float p = p0 + p1;
            p += __shfl_xor(p, 1, 64); p += __shfl_xor(p, 2, 64);
            p += __shfl_xor(p, 4, 64); p += __shfl_xor(p, 8, 64);
            if (sg == 0) yp[(size_t)t * XSTRIDE] = p;
        }
        __syncthreads();
    }
}

extern "C" void kernel_launch(void* const* d_in, const int* in_sizes, int n_in,
                              void* d_out, int out_size, void* d_ws, size_t ws_size,
                              hipStream_t stream) {
    const float* x  = (const float*)d_in[0];
    const float* A  = (const float*)d_in[1];
    const float* Bm = (const float*)d_in[2];
    const float* Cm = (const float*)d_in[3];
    const float* dp = (const float*)d_in[4];
    float* y = (float*)d_out;

    if (ws_size >= WS_REQ) {
        float* S_ws = (float*)d_ws;
        unsigned short* G_ws = (unsigned short*)((char*)d_ws + WS_S_BYTES);
        unsigned short* H_ws = G_ws + P128_ELEMS;
        hipLaunchKernelGGL(k1_chunk, dim3(BH * NC), dim3(256), 0, stream,
                           x, A, Bm, dp, S_ws, G_ws);
        hipLaunchKernelGGL(k2_scan, dim3(BH * 16), dim3(64), 0, stream,
                           S_ws, G_ws, H_ws);
        hipLaunchKernelGGL(k3_y, dim3(BH * NC), dim3(256), 0, stream,
                           x, Bm, Cm, S_ws, H_ws, y);
    } else {
        hipLaunchKernelGGL(ssm_scan_fb, dim3(BH * F_DBLK), dim3(256), 0, stream,
                           x, A, Bm, Cm, dp, y);
    }
}